// Round 9
// baseline (276.513 us; speedup 1.0000x reference)
//
#include <hip/hip_runtime.h>
#include <math.h>

#define NN 10000
#define NE 160000
#define NB 8
#define TT 12
#define HP 64
#define HV 32

typedef float v2 __attribute__((ext_vector_type(2)));

__device__ __forceinline__ v2 fma2(v2 a, v2 b, v2 c) { return __builtin_elementwise_fma(a, b, c); }

__device__ __forceinline__ void f4_to_v2(float4 a, float4 b, float4 c, v2* r2) {
  r2[0] = (v2){a.x, a.y}; r2[1] = (v2){a.z, a.w};
  r2[2] = (v2){b.x, b.y}; r2[3] = (v2){b.z, b.w};
  r2[4] = (v2){c.x, c.y}; r2[5] = (v2){c.z, c.w};
}

// ---------------- zero ONLY the accumulated buffers (den, pred) ----------------
__global__ __launch_bounds__(256) void k_init(float4* __restrict__ den4, float4* __restrict__ pred4) {
  int i = blockIdx.x * 256 + threadIdx.x;
  float4 z; z.x = 0.f; z.y = 0.f; z.z = 0.f; z.w = 0.f;
  if (i < NN * NB / 4) { den4[i] = z; pred4[i] = z; }
}

// ---------------- per-(node,batch) attention aggregates {A1,A2,Dsrc,Ddst}; block 0 writes consts ----------------
__global__ __launch_bounds__(256) void k_node(const float* __restrict__ feature,
                                              const float* __restrict__ fc_w,
                                              const float* __restrict__ attn_w,
                                              const float* __restrict__ ln2_g,
                                              const float* __restrict__ ln2_b,
                                              float4* __restrict__ nodeAgg,
                                              float* __restrict__ consts) {
  if (blockIdx.x == 0) {
    __shared__ float r1[256], r2[256];
    int c = threadIdx.x;
    float vg = 0.f, vb = 0.f;
    if (c < 2 * HP + 1) {
      float aw = attn_w[c];
      vg = aw * ln2_g[c];
      vb = aw * ln2_b[c];
    }
    r1[c] = vg; r2[c] = vb;
    __syncthreads();
    for (int off = 128; off > 0; off >>= 1) {
      if (c < off) { r1[c] += r1[c + off]; r2[c] += r2[c + off]; }
      __syncthreads();
    }
    if (c == 0) {
      consts[0] = r1[0];                                // S_wg
      consts[1] = r2[0];                                // S_wb
      consts[2] = attn_w[2 * HP] * ln2_g[2 * HP];       // wg for the T column
      consts[3] = 0.f;
    }
  }

  int t = blockIdx.x * 256 + threadIdx.x;
  if (t >= NN * NB) return;
  v2 row2[6];
  const float4* p4 = reinterpret_cast<const float4*>(feature + (size_t)t * TT);
  f4_to_v2(p4[0], p4[1], p4[2], row2);
  const v2* wv  = reinterpret_cast<const v2*>(fc_w);    // [64][6]
  const v2* awv = reinterpret_cast<const v2*>(attn_w);
  const v2* gv  = reinterpret_cast<const v2*>(ln2_g);
  v2 A1p = {0.f,0.f}, A2p = {0.f,0.f}, Dsp = {0.f,0.f}, Ddp = {0.f,0.f};
#pragma unroll
  for (int c2 = 0; c2 < HP / 2; ++c2) {
    v2 a0 = {0.f,0.f}, a1 = {0.f,0.f};
#pragma unroll
    for (int k2 = 0; k2 < 6; ++k2) {
      a0 = fma2(row2[k2], wv[(2 * c2) * 6 + k2], a0);
      a1 = fma2(row2[k2], wv[(2 * c2 + 1) * 6 + k2], a1);
    }
    v2 zp = {a0.x + a0.y, a1.x + a1.y};
    A1p += zp;
    A2p = fma2(zp, zp, A2p);
    v2 wgs = awv[c2] * gv[c2];
    v2 wgd = awv[HP / 2 + c2] * gv[HP / 2 + c2];
    Dsp = fma2(wgs, zp, Dsp);
    Ddp = fma2(wgd, zp, Ddp);
  }
  float4 o;
  o.x = A1p.x + A1p.y; o.y = A2p.x + A2p.y; o.z = Dsp.x + Dsp.y; o.w = Ddp.x + Ddp.y;
  nodeAgg[t] = o;
}

// ---------------- one NAM branch (packed-fp32, R4-exact op order) ----------------
__device__ __forceinline__ float nam_branch(const v2* row2, const float* __restrict__ w,
                                            const float* __restrict__ bias,
                                            const float* __restrict__ g,
                                            const float* __restrict__ bb,
                                            const float* __restrict__ w2, float b2) {
  const v2* wv    = reinterpret_cast<const v2*>(w);     // [32][6]
  const v2* biasv = reinterpret_cast<const v2*>(bias);
  const v2* gv    = reinterpret_cast<const v2*>(g);
  const v2* bbv   = reinterpret_cast<const v2*>(bb);
  const v2* w2v   = reinterpret_cast<const v2*>(w2);
  v2 hp[HV / 2];
  v2 sp1 = {0.f,0.f}, sp2 = {0.f,0.f};
#pragma unroll
  for (int j2 = 0; j2 < HV / 2; ++j2) {
    v2 a0 = {0.f,0.f}, a1 = {0.f,0.f};
#pragma unroll
    for (int k2 = 0; k2 < 6; ++k2) {
      a0 = fma2(row2[k2], wv[(2 * j2) * 6 + k2], a0);
      a1 = fma2(row2[k2], wv[(2 * j2 + 1) * 6 + k2], a1);
    }
    v2 bp = biasv[j2];
    v2 h = {a0.x + a0.y + bp.x, a1.x + a1.y + bp.y};
    hp[j2] = h;
    sp1 += h;
    sp2 = fma2(h, h, sp2);
  }
  float s1 = sp1.x + sp1.y, s2 = sp2.x + sp2.y;
  float m = s1 * (1.f / HV);
  float var = s2 * (1.f / HV) - m * m;
  float inv = rsqrtf(var + 1e-5f);
  v2 inv2 = {inv, inv};
  float nmi = -m * inv;
  v2 nmi2 = {nmi, nmi};
  v2 acc2 = {0.f,0.f};
  v2 zero = {0.f,0.f};
#pragma unroll
  for (int j2 = 0; j2 < HV / 2; ++j2) {
    v2 tt = fma2(hp[j2], inv2, nmi2);
    v2 y = fma2(tt, gv[j2], bbv[j2]);
    y = __builtin_elementwise_max(y, zero);
    acc2 = fma2(y, w2v[j2], acc2);
  }
  float acc = acc2.x + acc2.y + b2;
  return 1.f / (1.f + __expf(-acc));
}

// ---- epilogue for one (e,b) item: velocity -> T -> diffusion sum -> attention -> ex ----
__device__ __forceinline__ void edge_epilogue(float xu, float xd, float al, float dist,
                                              float4 f0, float4 f1, float4 f2,
                                              float4 As, float4 Ad,
                                              float c0, float c1, float c2w,
                                              float w30, float w31, float w32, float b3,
                                              float& ex_out, float& s_out) {
  float vp = fmaf(w30, xu, fmaf(w31, xd, fmaf(w32, al, b3)));
  float v = fmaxf(vp, 0.f) + log1pf(__expf(-fabsf(vp)));  // stable softplus
  v = fminf(v, 3.f);
  float Tt = dist / (v + 1e-5f);                           // IEEE div: rounding cliff below
  float Ti = fminf(fmaxf(rintf(Tt * 0.1f), 0.f), (float)(TT - 1));
  int n = TT - (int)Ti;  // 1..12
  float acl = fminf(fmaxf(al, 0.f), 1.f);
  float F = 1.f / (1.f + acl * Tt);
  float omF = 1.f - F;

  float row[TT];
  row[0]=f0.x; row[1]=f0.y; row[2]=f0.z; row[3]=f0.w;
  row[4]=f1.x; row[5]=f1.y; row[6]=f1.z; row[7]=f1.w;
  row[8]=f2.x; row[9]=f2.y; row[10]=f2.z; row[11]=f2.w;
  float pw = 1.f, s = 0.f;
#pragma unroll
  for (int k = TT - 1; k >= 0; --k) {
    if (k <= n - 1) { s = fmaf(pw, row[k], s); pw *= omF; }
  }
  s *= F;

  float s1 = As.x + Ad.x + Tt;
  float s2 = As.y + Ad.y + Tt * Tt;
  float sd = As.z + Ad.w + c2w * Tt;

  float m = s1 * (1.f / 129.f);
  float var = s2 * (1.f / 129.f) - m * m;
  float inv = rsqrtf(var + 1e-5f);
  float a = fmaf(inv, sd - m * c0, c1);
  a = (a >= 0.f) ? a : 0.01f * a;  // leaky_relu 0.01
  ex_out = __expf(a);              // |a| bounded -> no overflow, no segment-max needed
  s_out = s;
}

// ---------------- per-thread: TWO (e,b) items on the SAME edge (b pair) ----------------
__global__ __launch_bounds__(256) void k_edge1(
    const float* __restrict__ upstream, const float* __restrict__ downstream,
    const float* __restrict__ distance, const float* __restrict__ alpha,
    const int* __restrict__ src, const int* __restrict__ dst,
    const float* __restrict__ feature, const float4* __restrict__ nodeAgg,
    const float* __restrict__ l11_w, const float* __restrict__ l11_b,
    const float* __restrict__ ln11_g, const float* __restrict__ ln11_b,
    const float* __restrict__ l12_w, const float* __restrict__ l12_b,
    const float* __restrict__ l21_w, const float* __restrict__ l21_b,
    const float* __restrict__ ln21_g, const float* __restrict__ ln21_b,
    const float* __restrict__ l22_w, const float* __restrict__ l22_b,
    const float* __restrict__ l3_w, const float* __restrict__ l3_b,
    const float* __restrict__ consts,
    float* __restrict__ prod, float* __restrict__ den) {
  int t = blockIdx.x * 256 + threadIdx.x;          // [0, NE*NB/2)
  int e  = t >> 2;
  int bp = (t & 3) << 1;                           // b0 = bp, b1 = bp+1
  size_t q0 = (size_t)e * NB + bp;                 // item index of (e, b0)

  // ---- 1) streaming loads FIRST (oldest in vmcnt queue) ----
  const float4* up4 = reinterpret_cast<const float4*>(upstream + q0 * TT);    // 24 floats: b0|b1
  float4 u0 = up4[0], u1 = up4[1], u2 = up4[2], u3 = up4[3], u4 = up4[4], u5 = up4[5];
  const float4* dn4 = reinterpret_cast<const float4*>(downstream + q0 * TT);
  float4 d0 = dn4[0], d1 = dn4[1], d2 = dn4[2], d3 = dn4[3], d4 = dn4[4], d5 = dn4[5];

  // ---- 2) edge scalars (4 threads share each address -> broadcast) ----
  int se = src[e], de = dst[e];
  float al = alpha[e];
  float dist = distance[e];

  // ---- 3) gathers (dep on se/de); in flight under all 4 NAM computations ----
  const float4* fp4 = reinterpret_cast<const float4*>(feature + ((size_t)se * NB + bp) * TT);
  float4 f0 = fp4[0], f1 = fp4[1], f2 = fp4[2];    // item0 rows
  float4 f3 = fp4[3], f4 = fp4[4], f5 = fp4[5];    // item1 rows
  float4 As0 = nodeAgg[(size_t)se * NB + bp],  As1 = nodeAgg[(size_t)se * NB + bp + 1];
  float4 Ad0 = nodeAgg[(size_t)de * NB + bp],  Ad1 = nodeAgg[(size_t)de * NB + bp + 1];

  // ---- 4) four sequential NAM branches (h[] reused; VGPR-lean) ----
  v2 rr[6];
  f4_to_v2(u0, u1, u2, rr);
  float xu0 = nam_branch(rr, l11_w, l11_b, ln11_g, ln11_b, l12_w, l12_b[0]);
  f4_to_v2(d0, d1, d2, rr);
  float xd0 = nam_branch(rr, l21_w, l21_b, ln21_g, ln21_b, l22_w, l22_b[0]);
  f4_to_v2(u3, u4, u5, rr);
  float xu1 = nam_branch(rr, l11_w, l11_b, ln11_g, ln11_b, l12_w, l12_b[0]);
  f4_to_v2(d3, d4, d5, rr);
  float xd1 = nam_branch(rr, l21_w, l21_b, ln21_g, ln21_b, l22_w, l22_b[0]);

  // ---- 5) epilogues (gather results long since resident) ----
  float c0 = consts[0], c1 = consts[1], c2w = consts[2];
  float w30 = l3_w[0], w31 = l3_w[1], w32 = l3_w[2], b3 = l3_b[0];
  float ex0, s0, ex1, s1;
  edge_epilogue(xu0, xd0, al, dist, f0, f1, f2, As0, Ad0, c0, c1, c2w, w30, w31, w32, b3, ex0, s0);
  edge_epilogue(xu1, xd1, al, dist, f3, f4, f5, As1, Ad1, c0, c1, c2w, w30, w31, w32, b3, ex1, s1);

  float2 pr; pr.x = ex0 * s0; pr.y = ex1 * s1;
  *reinterpret_cast<float2*>(prod + q0) = pr;
  atomicAdd(&den[(size_t)se * NB + bp], ex0);
  atomicAdd(&den[(size_t)se * NB + bp + 1], ex1);
}

// ---------------- scatter: pred[dst] += prod / den[src] ----------------
__global__ __launch_bounds__(256) void k_edge2(const int* __restrict__ src,
                                               const int* __restrict__ dst,
                                               const float* __restrict__ prod,
                                               const float* __restrict__ den,
                                               float* __restrict__ pred) {
  int t = blockIdx.x * 256 + threadIdx.x;
  int e = t >> 3, b = t & 7;
  float p = prod[t] / den[(size_t)src[e] * NB + b];        // IEEE div
  atomicAdd(&pred[(size_t)dst[e] * NB + b], p);
}

extern "C" void kernel_launch(void* const* d_in, const int* in_sizes, int n_in,
                              void* d_out, int out_size, void* d_ws, size_t ws_size,
                              hipStream_t stream) {
  const float* feature   = (const float*)d_in[0];
  const float* upstream  = (const float*)d_in[1];
  const float* downstream= (const float*)d_in[2];
  const float* distance  = (const float*)d_in[3];
  const int*   src       = (const int*)d_in[4];
  const int*   dst       = (const int*)d_in[5];
  const float* alpha     = (const float*)d_in[6];
  const float* fc_w      = (const float*)d_in[7];
  const float* ln2_g     = (const float*)d_in[8];
  const float* ln2_b     = (const float*)d_in[9];
  const float* attn_w    = (const float*)d_in[10];
  const float* l11_w     = (const float*)d_in[11];
  const float* l11_b     = (const float*)d_in[12];
  const float* ln11_g    = (const float*)d_in[13];
  const float* ln11_b    = (const float*)d_in[14];
  const float* l12_w     = (const float*)d_in[15];
  const float* l12_b     = (const float*)d_in[16];
  const float* l21_w     = (const float*)d_in[17];
  const float* l21_b     = (const float*)d_in[18];
  const float* ln21_g    = (const float*)d_in[19];
  const float* ln21_b    = (const float*)d_in[20];
  const float* l22_w     = (const float*)d_in[21];
  const float* l22_b     = (const float*)d_in[22];
  const float* l3_w      = (const float*)d_in[23];
  const float* l3_b      = (const float*)d_in[24];
  float* pred = (float*)d_out;

  // ws layout (floats): nodeAgg[NN*NB*4] | prod[NE*NB] | den[NN*NB] | consts[4]
  float* ws = (float*)d_ws;
  float4* nodeAgg = (float4*)ws;
  float* prod   = ws + (size_t)NN * NB * 4;
  float* den    = prod + (size_t)NE * NB;
  float* consts = den + (size_t)NN * NB;

  k_init<<<(NN * NB / 4 + 255) / 256, 256, 0, stream>>>((float4*)den, (float4*)pred);
  k_node<<<(NN * NB + 255) / 256, 256, 0, stream>>>(feature, fc_w, attn_w, ln2_g, ln2_b,
                                                    nodeAgg, consts);

  int eb2 = NE * NB / 2;                           // 2 items per thread
  k_edge1<<<eb2 / 256, 256, 0, stream>>>(upstream, downstream, distance, alpha, src, dst,
                                         feature, nodeAgg,
                                         l11_w, l11_b, ln11_g, ln11_b, l12_w, l12_b,
                                         l21_w, l21_b, ln21_g, ln21_b, l22_w, l22_b,
                                         l3_w, l3_b, consts, prod, den);
  int eb = NE * NB;
  k_edge2<<<eb / 256, 256, 0, stream>>>(src, dst, prod, den, pred);
}